// Round 6
// baseline (107.542 us; speedup 1.0000x reference)
//
#include <hip/hip_runtime.h>
#include <hip/hip_bf16.h>
#include <stdint.h>

typedef __attribute__((ext_vector_type(8))) short short8;   // 8 bf16 MFMA operand
typedef __attribute__((ext_vector_type(4))) float floatx4;  // MFMA accumulator

__device__ __forceinline__ unsigned short bfu(float a) {
    return __builtin_bit_cast(unsigned short, __float2bfloat16(a));
}
__device__ __forceinline__ uint32_t pkbf(float a, float b) {
    return (uint32_t)bfu(a) | ((uint32_t)bfu(b) << 16);
}

// =====================  Cl(3,0) -> M2(C) (Pauli) isomorphism  =====================
// blades: a0=1 a1=e1 a2=e2 a3=e12 a4=e3 a5=e13 a6=e23 a7=e123
// Re m00=a0+a4 Im m00=a3+a7 | Re m01=a1-a5 Im m01=a6-a2
// Re m10=a1+a5 Im m10=a6+a2 | Re m11=a0-a4 Im m11=a7-a3
// K index: k = part*1024 + 2p + s
// Abuf[1024][2048]: row 2b+r, col k = (part? Im:Re) Mx[b,p](r,s)
// BT  [2048][2048]: row n = 4o+2partN+c, col k =
//     part0: (partN? Im:Re) Mw[p,o](s,c);  part1: (partN? Re:-Im) Mw[p,o](s,c)
// C[2b+r][4o+2partN+c] = (partN? Im:Re) of (Mx·Mw)(r,c).

// ---------------- Pass 1 (fused): x -> Abuf, W -> BT ----------------
__global__ __launch_bounds__(256) void pack_all(
    const float* __restrict__ x, const float* __restrict__ W,
    unsigned short* __restrict__ Abuf, unsigned short* __restrict__ BT)
{
    const int t = threadIdx.x;
    if (blockIdx.x < 512) {
        // ---- pack_x (verbatim round-5, proven) ----
        __shared__ unsigned short TX[4][1024];
        const int b = blockIdx.x;
        const float4* src = (const float4*)(x + ((size_t)b * 512 + 2 * t) * 8);
        float4 f[4] = {src[0], src[1], src[2], src[3]};
        #pragma unroll
        for (int pp = 0; pp < 2; ++pp) {
            const float a0 = f[2*pp].x, a1 = f[2*pp].y, a2 = f[2*pp].z, a3 = f[2*pp].w;
            const float a4 = f[2*pp+1].x, a5 = f[2*pp+1].y, a6 = f[2*pp+1].z, a7 = f[2*pp+1].w;
            const int c = 4 * t + 2 * pp;
            TX[0][c] = bfu(a0 + a4); TX[0][c+1] = bfu(a1 - a5);
            TX[1][c] = bfu(a3 + a7); TX[1][c+1] = bfu(a6 - a2);
            TX[2][c] = bfu(a1 + a5); TX[2][c+1] = bfu(a0 - a4);
            TX[3][c] = bfu(a6 + a2); TX[3][c+1] = bfu(a7 - a3);
        }
        __syncthreads();
        const int tr = t >> 6, off = (t & 63) * 16;
        uint4* dst = (uint4*)(Abuf + (size_t)(2*b + (tr >> 1)) * 2048 + (tr & 1) * 1024 + off);
        const uint4* s4 = (const uint4*)&TX[tr][off];
        dst[0] = s4[0]; dst[1] = s4[1];
    } else {
        // ---- pack_w: coalesced reads (o in low lane bits), scattered 16B writes ----
        const int wb = blockIdx.x - 512;      // 0..255
        const int pbase = (wb & 7) * 64;
        const int o0 = (wb >> 3) * 16;
        const int o = o0 + (t & 15);
        const int pc = t >> 4;
        float R[4][2][2], I[4][2][2];
        #pragma unroll
        for (int u = 0; u < 4; ++u) {
            const float4* src = (const float4*)(W + ((size_t)(pbase + pc * 4 + u) * 512 + o) * 8);
            float4 lo = src[0], hi = src[1];
            R[u][0][0] = lo.x + hi.x;  I[u][0][0] = lo.w + hi.w;
            R[u][0][1] = lo.y - hi.y;  I[u][0][1] = hi.z - lo.z;
            R[u][1][0] = lo.y + hi.y;  I[u][1][0] = hi.z + lo.z;
            R[u][1][1] = lo.x - hi.x;  I[u][1][1] = hi.w - lo.w;
        }
        const int kbase = 2 * pbase + pc * 8;
        #pragma unroll
        for (int part = 0; part < 2; ++part)
            #pragma unroll
            for (int pN = 0; pN < 2; ++pN)
                #pragma unroll
                for (int c = 0; c < 2; ++c) {
                    uint4 v; uint32_t* vv = (uint32_t*)&v;
                    #pragma unroll
                    for (int u = 0; u < 4; ++u) {
                        const float v0 = (part == 0) ? (pN ? I[u][0][c] : R[u][0][c])
                                                     : (pN ? R[u][0][c] : -I[u][0][c]);
                        const float v1 = (part == 0) ? (pN ? I[u][1][c] : R[u][1][c])
                                                     : (pN ? R[u][1][c] : -I[u][1][c]);
                        vv[u] = pkbf(v0, v1);
                    }
                    const int n = 4 * o + 2 * pN + c;
                    *(uint4*)&BT[(size_t)n * 2048 + part * 1024 + kbase] = v;
                }
    }
}

// =====================  Pass 2: barrier-free L2-direct GEMM  =====================
__global__ __launch_bounds__(512) void iso_gemm2(
    const unsigned short* __restrict__ AB,   // [1024][2048] bf16, M-major K-minor
    const unsigned short* __restrict__ BB,   // [2048][2048] bf16, N-major K-minor
    const float* __restrict__ bias,          // [512][8] f32
    float*       __restrict__ out)           // [512][512][8] f32
{
    __shared__ __align__(16) unsigned char smem[98304];   // epilogue only
    const int t = threadIdx.x, lane = t & 63, wave = t >> 6;
    const int wn = wave & 1;        // n-half (64 cols)
    const int g  = wave >> 1;       // K-quarter 0..3 (512 K each)
    const int l15 = lane & 15, q = lane >> 4;

    // XCD swizzle: per XCD 4 n-tiles x 8 m-tiles (A 2MB + B 2MB slice)
    const int lin = blockIdx.y * 16 + blockIdx.x;
    const int xcd = lin & 7, sx = lin >> 3;
    const int tn = (xcd & 3) * 4 + (sx & 3);
    const int tm = (xcd >> 2) * 8 + (sx >> 2);
    const int m0 = tm * 64, v0 = tn * 128;

    // per-lane row pointers (k varies along the row)
    const unsigned short* arow[4];
    const unsigned short* brow[4];
    #pragma unroll
    for (int f = 0; f < 4; ++f) {
        arow[f] = AB + (size_t)(m0 + f * 16 + l15) * 2048;
        brow[f] = BB + (size_t)(v0 + wn * 64 + f * 16 + l15) * 2048;
    }
    const int kbase = g * 512 + q * 8;    // this lane's first k element

    floatx4 acc[4][4] = {};
    short8 abuf[2][4], bbuf[2][4];

    #pragma unroll
    for (int f = 0; f < 4; ++f) {
        abuf[0][f] = *(const short8*)(arow[f] + kbase);
        bbuf[0][f] = *(const short8*)(brow[f] + kbase);
    }
    #pragma unroll 2
    for (int it = 0; it < 16; ++it) {     // 16 ksteps of K=32 per K-quarter
        const int cb = it & 1, nb = cb ^ 1;
        if (it < 15) {
            const int kk = kbase + (it + 1) * 32;
            #pragma unroll
            for (int f = 0; f < 4; ++f) {
                abuf[nb][f] = *(const short8*)(arow[f] + kk);
                bbuf[nb][f] = *(const short8*)(brow[f] + kk);
            }
        }
        #pragma unroll
        for (int fm = 0; fm < 4; ++fm)
            #pragma unroll
            for (int fn = 0; fn < 4; ++fn)
                acc[fm][fn] = __builtin_amdgcn_mfma_f32_16x16x32_bf16(
                    abuf[cb][fm], bbuf[cb][fn], acc[fm][fn], 0, 0, 0);
    }

    // ---- K-quarter reduction through LDS: regions r=(g-1)*2+wn, 16KB each ----
    __syncthreads();
    if (g > 0) {
        float* r = (float*)(smem + ((g - 1) * 2 + wn) * 16384);
        #pragma unroll
        for (int f = 0; f < 16; ++f)
            *(floatx4*)&r[f * 256 + lane * 4] = acc[f >> 2][f & 3];
    }
    __syncthreads();
    if (g == 0) {
        #pragma unroll
        for (int gg = 1; gg < 4; ++gg) {
            const float* r = (const float*)(smem + ((gg - 1) * 2 + wn) * 16384);
            #pragma unroll
            for (int f = 0; f < 16; ++f)
                acc[f >> 2][f & 3] += *(const floatx4*)&r[f * 256 + lane * 4];
        }
    }
    __syncthreads();
    float* Cf = (float*)smem;                     // [64][130] f32 (33 KB)
    if (g == 0) {
        #pragma unroll
        for (int fm = 0; fm < 4; ++fm)
            #pragma unroll
            for (int fn = 0; fn < 4; ++fn)
                #pragma unroll
                for (int rr = 0; rr < 4; ++rr) {
                    const int row = fm * 16 + q * 4 + rr;
                    const int col = wn * 64 + fn * 16 + l15;
                    Cf[row * 130 + col] = acc[fm][fn][rr];
                }
    }
    __syncthreads();
    // ---- inverse map + bias (verbatim round-5, proven): 32 b x 32 o ----
    const int b0 = m0 >> 1, o0 = v0 >> 2;
    #pragma unroll
    for (int rnd = 0; rnd < 2; ++rnd) {
        const int pi = rnd * 512 + t;
        const int o_l = pi & 31, b_l = pi >> 5;
        const float* r0 = &Cf[(2 * b_l) * 130 + 4 * o_l];
        const float* r1 = r0 + 130;
        const float Cr00 = r0[0], Cr01 = r0[1], Ci00 = r0[2], Ci01 = r0[3];
        const float Cr10 = r1[0], Cr11 = r1[1], Ci10 = r1[2], Ci11 = r1[3];
        const float a0 = 0.5f * (Cr00 + Cr11), a7 = 0.5f * (Ci00 + Ci11);
        const float a4 = 0.5f * (Cr00 - Cr11), a3 = 0.5f * (Ci00 - Ci11);
        const float a1 = 0.5f * (Cr01 + Cr10), a6 = 0.5f * (Ci01 + Ci10);
        const float a2 = 0.5f * (Ci10 - Ci01), a5 = 0.5f * (Cr10 - Cr01);
        const int o = o0 + o_l, b = b0 + b_l;
        const float* bp = bias + o * 8;
        float4 lo = {a0 + bp[0], a1 + bp[1], a2 + bp[2], a3 + bp[3]};
        float4 hi = {a4 + bp[4], a5 + bp[5], a6 + bp[6], a7 + bp[7]};
        float* op = out + ((size_t)b * 512 + o) * 8;
        *(float4*)op = lo;
        *(float4*)(op + 4) = hi;
    }
}

// =====================  Fallback (verified round-2 kernel)  =====================
__device__ __align__(16) const uint32_t SGN[4][4] = {
    {0x00000000u, 0x80000000u, 0x80000000u, 0x80008000u},
    {0x80000000u, 0x00000000u, 0x00000000u, 0x00008000u},
    {0x80000000u, 0x80008000u, 0x00000000u, 0x80000000u},
    {0x00000000u, 0x00008000u, 0x80000000u, 0x00000000u},
};
__device__ __forceinline__ uint32_t swap16(uint32_t a) { return (a >> 16) | (a << 16); }
__device__ __forceinline__ uint4 xperm2(uint4 v, int kp) {
    const bool s1 = (kp & 1) != 0;
    uint32_t x1 = s1 ? v.y : v.x, y1 = s1 ? v.x : v.y, z1 = s1 ? v.w : v.z, w1 = s1 ? v.z : v.w;
    const bool s2 = (kp & 2) != 0;
    uint4 r; r.x = s2 ? z1 : x1; r.y = s2 ? w1 : y1; r.z = s2 ? x1 : z1; r.w = s2 ? y1 : w1;
    return r;
}
__global__ __launch_bounds__(512) void gp_linear_legacy(
    const float* __restrict__ xg_raw, const float* __restrict__ wg,
    const float* __restrict__ bias, float* __restrict__ out)
{
    __shared__ __align__(16) unsigned short As[128 * 64];
    __shared__ __align__(16) unsigned short Bs[8 * 64 * 8];
    const int t = threadIdx.x, lane = t & 63, wave = t >> 6;
    const int m0 = blockIdx.y * 128, n0 = blockIdx.x * 64;
    const int ap = t & 7, akp = (t >> 3) & 3, ab = t >> 5, ak0 = akp * 2;
    const uint4 mask = *(const uint4*)SGN[akp];
    const int wm = wave & 3, wnn = wave >> 2, l15 = lane & 15, q = lane >> 4;
    floatx4 acc[2][2] = {};
    const float4* xg = (const float4*)xg_raw;
    const int bg0 = m0 >> 3;
    float4 ax0, ax1, bw0, bw1;
    {
        const size_t aidx = ((size_t)(bg0 + ab) * 512 + ap) * 2;
        ax0 = xg[aidx]; ax1 = xg[aidx + 1];
        const float* gsrc = wg + (((size_t)wave * 512 + n0) << 3) + (lane << 3);
        bw0 = *(const float4*)gsrc; bw1 = *(const float4*)(gsrc + 4);
    }
    for (int kt = 0; kt < 64; ++kt) {
        __syncthreads();
        {
            uint4 v;
            v.x = pkbf(ax0.x, ax0.y); v.y = pkbf(ax0.z, ax0.w);
            v.z = pkbf(ax1.x, ax1.y); v.w = pkbf(ax1.z, ax1.w);
            uint4 pk = xperm2(v, akp), r0, p1, r1;
            r0.x = pk.x ^ mask.x; r0.y = pk.y ^ mask.y; r0.z = pk.z ^ mask.z; r0.w = pk.w ^ mask.w;
            p1.x = swap16(pk.x); p1.y = swap16(pk.y); p1.z = swap16(pk.z); p1.w = swap16(pk.w);
            r1.x = p1.x ^ mask.x; r1.y = p1.y ^ mask.y; r1.z = p1.z ^ mask.z; r1.w = p1.w ^ mask.w;
            const int row0 = ab * 8 + ak0;
            *(uint4*)&As[row0 * 64 + ((ap ^ ak0) << 3)] = r0;
            *(uint4*)&As[(row0 + 1) * 64 + ((ap ^ (ak0 + 1)) << 3)] = r1;
        }
        {
            uint4 b0;
            b0.x = pkbf(bw0.x, bw0.y); b0.y = pkbf(bw0.z, bw0.w);
            b0.z = pkbf(bw1.x, bw1.y); b0.w = pkbf(bw1.z, bw1.w);
            *(uint4*)&Bs[t << 3] = b0;
        }
        __syncthreads();
        if (kt + 1 < 64) {
            const int p0n = (kt + 1) * 8;
            const size_t aidx = ((size_t)(bg0 + ab) * 512 + p0n + ap) * 2;
            ax0 = xg[aidx]; ax1 = xg[aidx + 1];
            const float* gsrc = wg + (((size_t)(p0n + wave) * 512 + n0) << 3) + (lane << 3);
            bw0 = *(const float4*)gsrc; bw1 = *(const float4*)(gsrc + 4);
        }
        #pragma unroll
        for (int ks = 0; ks < 2; ++ks) {
            const int cb = ks * 4 + q;
            short8 a[2], bfr[2];
            #pragma unroll
            for (int fm = 0; fm < 2; ++fm) {
                const int row = wm * 32 + fm * 16 + l15;
                a[fm] = *(const short8*)&As[row * 64 + ((cb ^ (l15 & 7)) << 3)];
            }
            #pragma unroll
            for (int fn = 0; fn < 2; ++fn) {
                const int nl = wnn * 32 + fn * 16 + l15;
                bfr[fn] = *(const short8*)&Bs[((cb * 64) + nl) << 3];
            }
            #pragma unroll
            for (int fm = 0; fm < 2; ++fm)
                #pragma unroll
                for (int fn = 0; fn < 2; ++fn)
                    acc[fm][fn] = __builtin_amdgcn_mfma_f32_16x16x32_bf16(a[fm], bfr[fn], acc[fm][fn], 0, 0, 0);
        }
    }
    #pragma unroll
    for (int fm = 0; fm < 2; ++fm)
        #pragma unroll
        for (int fn = 0; fn < 2; ++fn) {
            const int n = n0 + wnn * 32 + fn * 16 + l15;
            #pragma unroll
            for (int r = 0; r < 4; ++r) {
                const int m = m0 + wm * 32 + fm * 16 + q * 4 + r;
                const int bi = m >> 3, k = m & 7;
                out[(size_t)bi * 4096 + n * 8 + k] = acc[fm][fn][r] + bias[n * 8 + k];
            }
        }
}

extern "C" void kernel_launch(void* const* d_in, const int* in_sizes, int n_in,
                              void* d_out, int out_size, void* d_ws, size_t ws_size,
                              hipStream_t stream) {
    const float* x  = (const float*)d_in[0];
    const float* W  = (const float*)d_in[1];
    const float* bb = (const float*)d_in[2];
    float* out = (float*)d_out;

    const size_t abytes = (size_t)1024 * 2048 * sizeof(unsigned short);  // 4 MB
    const size_t bbytes = (size_t)2048 * 2048 * sizeof(unsigned short);  // 8 MB
    if (ws_size >= abytes + bbytes) {
        unsigned short* Abuf = (unsigned short*)d_ws;
        unsigned short* Bbuf = (unsigned short*)((char*)d_ws + abytes);
        pack_all<<<768, 256, 0, stream>>>(x, W, Abuf, Bbuf);
        iso_gemm2<<<dim3(16, 16), 512, 0, stream>>>(Abuf, Bbuf, bb, out);
    } else {
        gp_linear_legacy<<<dim3(8, 32), dim3(512), 0, stream>>>(x, W, bb, out);
    }
}

// Round 7
// 89.617 us; speedup vs baseline: 1.2000x; 1.2000x over previous
//
#include <hip/hip_runtime.h>
#include <hip/hip_bf16.h>
#include <stdint.h>

typedef __attribute__((ext_vector_type(8))) short short8;   // 8 bf16 MFMA operand
typedef __attribute__((ext_vector_type(4))) float floatx4;  // MFMA accumulator

__device__ __forceinline__ unsigned short bfu(float a) {
    return __builtin_bit_cast(unsigned short, __float2bfloat16(a));
}
__device__ __forceinline__ uint32_t pkbf(float a, float b) {
    return (uint32_t)bfu(a) | ((uint32_t)bfu(b) << 16);
}

// =====================  Cl(3,0) -> M2(C) (Pauli) isomorphism  =====================
// blades: a0=1 a1=e1 a2=e2 a3=e12 a4=e3 a5=e13 a6=e23 a7=e123
// Re m00=a0+a4 Im m00=a3+a7 | Re m01=a1-a5 Im m01=a6-a2
// Re m10=a1+a5 Im m10=a6+a2 | Re m11=a0-a4 Im m11=a7-a3
// K index: k = part*1024 + 2p + s
// Abuf[1024][2048]: row 2b+r, col k = (part? Im:Re) Mx[b,p](r,s)
// BT  [2048][2048]: row n = 4o+2partN+c, col k =
//     part0: (partN? Im:Re) Mw[p,o](s,c);  part1: (partN? Re:-Im) Mw[p,o](s,c)
// C[2b+r][4o+2partN+c] = (partN? Im:Re) of (Mx·Mw)(r,c).

// ---------------- Pass 1 (fused): x -> Abuf, W -> BT  (verified round-5/6) ----------------
__global__ __launch_bounds__(256) void pack_all(
    const float* __restrict__ x, const float* __restrict__ W,
    unsigned short* __restrict__ Abuf, unsigned short* __restrict__ BT)
{
    const int t = threadIdx.x;
    if (blockIdx.x < 512) {
        __shared__ unsigned short TX[4][1024];
        const int b = blockIdx.x;
        const float4* src = (const float4*)(x + ((size_t)b * 512 + 2 * t) * 8);
        float4 f[4] = {src[0], src[1], src[2], src[3]};
        #pragma unroll
        for (int pp = 0; pp < 2; ++pp) {
            const float a0 = f[2*pp].x, a1 = f[2*pp].y, a2 = f[2*pp].z, a3 = f[2*pp].w;
            const float a4 = f[2*pp+1].x, a5 = f[2*pp+1].y, a6 = f[2*pp+1].z, a7 = f[2*pp+1].w;
            const int c = 4 * t + 2 * pp;
            TX[0][c] = bfu(a0 + a4); TX[0][c+1] = bfu(a1 - a5);
            TX[1][c] = bfu(a3 + a7); TX[1][c+1] = bfu(a6 - a2);
            TX[2][c] = bfu(a1 + a5); TX[2][c+1] = bfu(a0 - a4);
            TX[3][c] = bfu(a6 + a2); TX[3][c+1] = bfu(a7 - a3);
        }
        __syncthreads();
        const int tr = t >> 6, off = (t & 63) * 16;
        uint4* dst = (uint4*)(Abuf + (size_t)(2*b + (tr >> 1)) * 2048 + (tr & 1) * 1024 + off);
        const uint4* s4 = (const uint4*)&TX[tr][off];
        dst[0] = s4[0]; dst[1] = s4[1];
    } else {
        const int wb = blockIdx.x - 512;
        const int pbase = (wb & 7) * 64;
        const int o0 = (wb >> 3) * 16;
        const int o = o0 + (t & 15);
        const int pc = t >> 4;
        float R[4][2][2], I[4][2][2];
        #pragma unroll
        for (int u = 0; u < 4; ++u) {
            const float4* src = (const float4*)(W + ((size_t)(pbase + pc * 4 + u) * 512 + o) * 8);
            float4 lo = src[0], hi = src[1];
            R[u][0][0] = lo.x + hi.x;  I[u][0][0] = lo.w + hi.w;
            R[u][0][1] = lo.y - hi.y;  I[u][0][1] = hi.z - lo.z;
            R[u][1][0] = lo.y + hi.y;  I[u][1][0] = hi.z + lo.z;
            R[u][1][1] = lo.x - hi.x;  I[u][1][1] = hi.w - lo.w;
        }
        const int kbase = 2 * pbase + pc * 8;
        #pragma unroll
        for (int part = 0; part < 2; ++part)
            #pragma unroll
            for (int pN = 0; pN < 2; ++pN)
                #pragma unroll
                for (int c = 0; c < 2; ++c) {
                    uint4 v; uint32_t* vv = (uint32_t*)&v;
                    #pragma unroll
                    for (int u = 0; u < 4; ++u) {
                        const float v0 = (part == 0) ? (pN ? I[u][0][c] : R[u][0][c])
                                                     : (pN ? R[u][0][c] : -I[u][0][c]);
                        const float v1 = (part == 0) ? (pN ? I[u][1][c] : R[u][1][c])
                                                     : (pN ? R[u][1][c] : -I[u][1][c]);
                        vv[u] = pkbf(v0, v1);
                    }
                    const int n = 4 * o + 2 * pN + c;
                    *(uint4*)&BT[(size_t)n * 2048 + part * 1024 + kbase] = v;
                }
    }
}

// =====================  Pass 2: 64x64 tile, 2 blocks/CU, GLL-staged GEMM  =====================
#define GLL(src, dstoff) \
    __builtin_amdgcn_global_load_lds((const __attribute__((address_space(1))) uint32_t*)(src), \
        (__attribute__((address_space(3))) uint32_t*)(smem + (dstoff)), 16, 0, 0)

__global__ __launch_bounds__(256, 2) void iso_gemm3(
    const unsigned short* __restrict__ AB,   // [1024][2048] bf16, M-major K-minor
    const unsigned short* __restrict__ BB,   // [2048][2048] bf16, N-major K-minor
    const float* __restrict__ bias,          // [512][8] f32
    float*       __restrict__ out)           // [512][512][8] f32
{
    // buffer kt&1 at *32768: A 64 rows x 16 slots x 16B (16 KB) @0; B @16384
    __shared__ __align__(16) unsigned char smem[65536];
    const int t = threadIdx.x, lane = t & 63, wave = t >> 6;  // 4 waves
    const int g = wave;                  // K-group 0..3 (each K=512 total, K=32/slab)
    const int l15 = lane & 15, q = lane >> 4;

    // XCD swizzle: 8 regions of 8m x 8n tiles (A 2MB + B 2MB unique per XCD)
    const int lin = blockIdx.y * 32 + blockIdx.x;        // grid (32,16) = 512
    const int xcd = lin & 7, sx = lin >> 3;              // sx 0..63
    const int tm = (xcd >> 2) * 8 + (sx & 7);            // 0..15
    const int tn = (xcd & 3) * 8 + (sx >> 3);            // 0..31
    const int m0 = tm * 64, v0 = tn * 64;

    // staging: 32 GLL/slab (A 16 + B 16), 8 per wave; slot = chunk ^ (row&7)
    const unsigned short* a_srcs[4]; int a_dst[4];
    const unsigned short* b_srcs[4]; int b_dst[4];
    #pragma unroll
    for (int i = 0; i < 4; ++i) {
        const int sid = (wave * 4 + i) * 64 + lane;      // 0..1023
        const int row = sid >> 4, slot = sid & 15, chunk = slot ^ (row & 7);
        a_srcs[i] = AB + (size_t)(m0 + row) * 2048 + chunk * 8;
        a_dst[i] = (wave * 4 + i) * 1024;
        b_srcs[i] = BB + (size_t)(v0 + row) * 2048 + chunk * 8;
        b_dst[i] = 16384 + (wave * 4 + i) * 1024;
    }

    // frag-read constants: chunk = g*4+q, slot = chunk ^ (l15&7)
    const int slot = (g * 4 + q) ^ (l15 & 7);
    const int a_off = l15 * 256 + slot * 16;
    const int b_off = 16384 + l15 * 256 + slot * 16;

    floatx4 acc[4][4] = {};

    #pragma unroll
    for (int i = 0; i < 4; ++i) { GLL(a_srcs[i], a_dst[i]); GLL(b_srcs[i], b_dst[i]); }

    for (int kt = 0; kt < 16; ++kt) {
        __syncthreads();                         // drains vmcnt: buf[kt] ready
        const int cur = (kt & 1) * 32768;
        if (kt + 1 < 16) {
            const int nxt = ((kt + 1) & 1) * 32768;
            const int poff = (kt + 1) * 128;     // k elements per slab
            #pragma unroll
            for (int i = 0; i < 4; ++i) {
                GLL(a_srcs[i] + poff, nxt + a_dst[i]);
                GLL(b_srcs[i] + poff, nxt + b_dst[i]);
            }
        }
        short8 af[4], bf[4];
        #pragma unroll
        for (int fm = 0; fm < 4; ++fm)
            af[fm] = *(const short8*)&smem[cur + a_off + fm * 4096];
        #pragma unroll
        for (int fn = 0; fn < 4; ++fn)
            bf[fn] = *(const short8*)&smem[cur + b_off + fn * 4096];
        #pragma unroll
        for (int fm = 0; fm < 4; ++fm)
            #pragma unroll
            for (int fn = 0; fn < 4; ++fn)
                acc[fm][fn] = __builtin_amdgcn_mfma_f32_16x16x32_bf16(
                    af[fm], bf[fn], acc[fm][fn], 0, 0, 0);
    }

    // ---- 4-way K-group reduction: g=1..3 dump 16KB regions, g=0 sums ----
    __syncthreads();
    if (g > 0) {
        float* r = (float*)(smem + (g - 1) * 16384);
        #pragma unroll
        for (int f = 0; f < 16; ++f)
            *(floatx4*)&r[f * 256 + lane * 4] = acc[f >> 2][f & 3];
    }
    __syncthreads();
    if (g == 0) {
        #pragma unroll
        for (int gg = 1; gg < 4; ++gg) {
            const float* r = (const float*)(smem + (gg - 1) * 16384);
            #pragma unroll
            for (int f = 0; f < 16; ++f)
                acc[f >> 2][f & 3] += *(const floatx4*)&r[f * 256 + lane * 4];
        }
    }
    __syncthreads();
    float* Cf = (float*)smem;                    // [64][66] f32 (16.9 KB)
    if (g == 0) {
        #pragma unroll
        for (int fm = 0; fm < 4; ++fm)
            #pragma unroll
            for (int fn = 0; fn < 4; ++fn)
                #pragma unroll
                for (int rr = 0; rr < 4; ++rr) {
                    const int row = fm * 16 + q * 4 + rr;
                    const int col = fn * 16 + l15;
                    Cf[row * 66 + col] = acc[fm][fn][rr];
                }
    }
    __syncthreads();
    // ---- inverse map + bias: tile = 32 b x 16 o; 512 pairs, 2 per thread ----
    const int b0 = m0 >> 1, o0 = v0 >> 2;
    #pragma unroll
    for (int rnd = 0; rnd < 2; ++rnd) {
        const int pi = rnd * 256 + t;
        const int o_l = pi & 15, b_l = pi >> 4;
        const float* r0 = &Cf[(2 * b_l) * 66 + 4 * o_l];
        const float* r1 = r0 + 66;
        const float Cr00 = r0[0], Cr01 = r0[1], Ci00 = r0[2], Ci01 = r0[3];
        const float Cr10 = r1[0], Cr11 = r1[1], Ci10 = r1[2], Ci11 = r1[3];
        const float a0 = 0.5f * (Cr00 + Cr11), a7 = 0.5f * (Ci00 + Ci11);
        const float a4 = 0.5f * (Cr00 - Cr11), a3 = 0.5f * (Ci00 - Ci11);
        const float a1 = 0.5f * (Cr01 + Cr10), a6 = 0.5f * (Ci01 + Ci10);
        const float a2 = 0.5f * (Ci10 - Ci01), a5 = 0.5f * (Cr10 - Cr01);
        const int o = o0 + o_l, b = b0 + b_l;
        const float* bp = bias + o * 8;
        float4 lo = {a0 + bp[0], a1 + bp[1], a2 + bp[2], a3 + bp[3]};
        float4 hi = {a4 + bp[4], a5 + bp[5], a6 + bp[6], a7 + bp[7]};
        float* op = out + ((size_t)b * 512 + o) * 8;
        *(float4*)op = lo;
        *(float4*)(op + 4) = hi;
    }
}

// =====================  Fallback (verified round-2 kernel)  =====================
__device__ __align__(16) const uint32_t SGN[4][4] = {
    {0x00000000u, 0x80000000u, 0x80000000u, 0x80008000u},
    {0x80000000u, 0x00000000u, 0x00000000u, 0x00008000u},
    {0x80000000u, 0x80008000u, 0x00000000u, 0x80000000u},
    {0x00000000u, 0x00008000u, 0x80000000u, 0x00000000u},
};
__device__ __forceinline__ uint32_t swap16(uint32_t a) { return (a >> 16) | (a << 16); }
__device__ __forceinline__ uint4 xperm2(uint4 v, int kp) {
    const bool s1 = (kp & 1) != 0;
    uint32_t x1 = s1 ? v.y : v.x, y1 = s1 ? v.x : v.y, z1 = s1 ? v.w : v.z, w1 = s1 ? v.z : v.w;
    const bool s2 = (kp & 2) != 0;
    uint4 r; r.x = s2 ? z1 : x1; r.y = s2 ? w1 : y1; r.z = s2 ? x1 : z1; r.w = s2 ? y1 : w1;
    return r;
}
__global__ __launch_bounds__(512) void gp_linear_legacy(
    const float* __restrict__ xg_raw, const float* __restrict__ wg,
    const float* __restrict__ bias, float* __restrict__ out)
{
    __shared__ __align__(16) unsigned short As[128 * 64];
    __shared__ __align__(16) unsigned short Bs[8 * 64 * 8];
    const int t = threadIdx.x, lane = t & 63, wave = t >> 6;
    const int m0 = blockIdx.y * 128, n0 = blockIdx.x * 64;
    const int ap = t & 7, akp = (t >> 3) & 3, ab = t >> 5, ak0 = akp * 2;
    const uint4 mask = *(const uint4*)SGN[akp];
    const int wm = wave & 3, wnn = wave >> 2, l15 = lane & 15, q = lane >> 4;
    floatx4 acc[2][2] = {};
    const float4* xg = (const float4*)xg_raw;
    const int bg0 = m0 >> 3;
    float4 ax0, ax1, bw0, bw1;
    {
        const size_t aidx = ((size_t)(bg0 + ab) * 512 + ap) * 2;
        ax0 = xg[aidx]; ax1 = xg[aidx + 1];
        const float* gsrc = wg + (((size_t)wave * 512 + n0) << 3) + (lane << 3);
        bw0 = *(const float4*)gsrc; bw1 = *(const float4*)(gsrc + 4);
    }
    for (int kt = 0; kt < 64; ++kt) {
        __syncthreads();
        {
            uint4 v;
            v.x = pkbf(ax0.x, ax0.y); v.y = pkbf(ax0.z, ax0.w);
            v.z = pkbf(ax1.x, ax1.y); v.w = pkbf(ax1.z, ax1.w);
            uint4 pk = xperm2(v, akp), r0, p1, r1;
            r0.x = pk.x ^ mask.x; r0.y = pk.y ^ mask.y; r0.z = pk.z ^ mask.z; r0.w = pk.w ^ mask.w;
            p1.x = swap16(pk.x); p1.y = swap16(pk.y); p1.z = swap16(pk.z); p1.w = swap16(pk.w);
            r1.x = p1.x ^ mask.x; r1.y = p1.y ^ mask.y; r1.z = p1.z ^ mask.z; r1.w = p1.w ^ mask.w;
            const int row0 = ab * 8 + ak0;
            *(uint4*)&As[row0 * 64 + ((ap ^ ak0) << 3)] = r0;
            *(uint4*)&As[(row0 + 1) * 64 + ((ap ^ (ak0 + 1)) << 3)] = r1;
        }
        {
            uint4 b0;
            b0.x = pkbf(bw0.x, bw0.y); b0.y = pkbf(bw0.z, bw0.w);
            b0.z = pkbf(bw1.x, bw1.y); b0.w = pkbf(bw1.z, bw1.w);
            *(uint4*)&Bs[t << 3] = b0;
        }
        __syncthreads();
        if (kt + 1 < 64) {
            const int p0n = (kt + 1) * 8;
            const size_t aidx = ((size_t)(bg0 + ab) * 512 + p0n + ap) * 2;
            ax0 = xg[aidx]; ax1 = xg[aidx + 1];
            const float* gsrc = wg + (((size_t)(p0n + wave) * 512 + n0) << 3) + (lane << 3);
            bw0 = *(const float4*)gsrc; bw1 = *(const float4*)(gsrc + 4);
        }
        #pragma unroll
        for (int ks = 0; ks < 2; ++ks) {
            const int cb = ks * 4 + q;
            short8 a[2], bfr[2];
            #pragma unroll
            for (int fm = 0; fm < 2; ++fm) {
                const int row = wm * 32 + fm * 16 + l15;
                a[fm] = *(const short8*)&As[row * 64 + ((cb ^ (l15 & 7)) << 3)];
            }
            #pragma unroll
            for (int fn = 0; fn < 2; ++fn) {
                const int nl = wnn * 32 + fn * 16 + l15;
                bfr[fn] = *(const short8*)&Bs[((cb * 64) + nl) << 3];
            }
            #pragma unroll
            for (int fm = 0; fm < 2; ++fm)
                #pragma unroll
                for (int fn = 0; fn < 2; ++fn)
                    acc[fm][fn] = __builtin_amdgcn_mfma_f32_16x16x32_bf16(a[fm], bfr[fn], acc[fm][fn], 0, 0, 0);
        }
    }
    #pragma unroll
    for (int fm = 0; fm < 2; ++fm)
        #pragma unroll
        for (int fn = 0; fn < 2; ++fn) {
            const int n = n0 + wnn * 32 + fn * 16 + l15;
            #pragma unroll
            for (int r = 0; r < 4; ++r) {
                const int m = m0 + wm * 32 + fm * 16 + q * 4 + r;
                const int bi = m >> 3, k = m & 7;
                out[(size_t)bi * 4096 + n * 8 + k] = acc[fm][fn][r] + bias[n * 8 + k];
            }
        }
}

extern "C" void kernel_launch(void* const* d_in, const int* in_sizes, int n_in,
                              void* d_out, int out_size, void* d_ws, size_t ws_size,
                              hipStream_t stream) {
    const float* x  = (const float*)d_in[0];
    const float* W  = (const float*)d_in[1];
    const float* bb = (const float*)d_in[2];
    float* out = (float*)d_out;

    const size_t abytes = (size_t)1024 * 2048 * sizeof(unsigned short);  // 4 MB
    const size_t bbytes = (size_t)2048 * 2048 * sizeof(unsigned short);  // 8 MB
    if (ws_size >= abytes + bbytes) {
        unsigned short* Abuf = (unsigned short*)d_ws;
        unsigned short* Bbuf = (unsigned short*)((char*)d_ws + abytes);
        pack_all<<<768, 256, 0, stream>>>(x, W, Abuf, Bbuf);
        iso_gemm3<<<dim3(32, 16), 256, 0, stream>>>(Abuf, Bbuf, bb, out);
    } else {
        gp_linear_legacy<<<dim3(8, 32), dim3(512), 0, stream>>>(x, W, bb, out);
    }
}